// Round 7
// baseline (1462.398 us; speedup 1.0000x reference)
//
#include <hip/hip_runtime.h>

// GraphVAE: GCN-VAE encoder + edge decoder + 50-iter MPM fixed point.
//
// Round-7: STOP SYNCING. Six protocol variants (r0/r1/r2/r4/r6) all cost
// 7-10us per device-wide exchange round; per-iteration distributed compute
// is only ~0.25us. The MPM update from a full X is ~1.5M lane-ops -> ONE CU
// does it in ~4-5us/iter, cheaper than the cheapest measured sync. So:
//  * encoder stays distributed across 20 blocks (3 proven gbar barriers),
//  * block 0 then computes the ENTIRE MPM alone (TPB=640 = 8*80: thread <->
//    (a = tid%80, rows i = tid/80 + 8k)); blocks 1-19 release and exit.
//  * B row in 80 VGPRs/thread; X,M in LDS (row-major, pad 84 -> broadcast/
//    contiguous accesses, no conflicts); adjacency as per-row neighbor lists
//    interleaved by j%4 residue (preserves the EXACT e0..e3 ascending-j
//    summation order of r0-r6; pad entries point at a zero M-row -> +0.0).
//  * 2 __syncthreads per iteration, ZERO global traffic in the loop.
// Arithmetic per entry identical to r0-r6; only the norm-reduction grouping
// changes (ulp-level -- r0's nondeterministic atomic norm already passed).

#define NN 80
#define PBLK 20            // blocks: encoder distribution (MPM: block 0 only)
#define TPB 640            // 10 waves; MPM: a = tid%80, i0 = tid/80 (640=8*80)
#define RP 84              // LDS row pad
#define NCOLS 13           // encoder: owned feature columns per block
#define AGT __HIP_MEMORY_SCOPE_AGENT
#define SPIN_MAX (1<<22)   // hang-breaker on all global spins

__device__ __forceinline__ void gbar(int* ctr, int target){
  __syncthreads();
  if (threadIdx.x == 0){
    __hip_atomic_fetch_add(ctr, 1, __ATOMIC_RELEASE, AGT);
    int spins = 0;
    while (__hip_atomic_load(ctr, __ATOMIC_RELAXED, AGT) < target){
      __builtin_amdgcn_s_sleep(1);
      if (++spins > SPIN_MAX) break;
    }
    (void)__hip_atomic_load(ctr, __ATOMIC_ACQUIRE, AGT);  // one inv
  }
  __syncthreads();
}

__device__ __forceinline__ float wave_sum(float v){
  #pragma unroll
  for (int k = 32; k >= 1; k >>= 1) v += __shfl_xor(v, k, 64);
  return v;
}

// GCN aggregate (+self loop) + bias + BatchNorm(train, biased var) + ReLU for
// this block's owned feature columns. inL: LDS [NCOLS][80] (pre-aggregation,
// own columns). outT: global transposed [256][80].
__device__ void gcn_bn_relu(const float* inL, float* outT,
                            const float* bias, const float* gamma, const float* beta,
                            const int* ei, const float* dinv,
                            float* accL, float* colstat, int p, int tid)
{
  for (int u = tid; u < NCOLS*NN; u += TPB) accL[u] = 0.f;
  __syncthreads();
  for (int cl = 0; cl < NCOLS; cl++){
    int c = p + PBLK*cl; if (c >= 256) break;
    const float* col = &inL[cl*NN];
    for (int e = tid; e < 800; e += TPB){
      int sidx = ei[e], didx = ei[800+e];
      atomicAdd(&accL[cl*NN + didx], col[sidx]*dinv[sidx]*dinv[didx]);
    }
  }
  __syncthreads();
  for (int u = tid; u < NCOLS*NN; u += TPB){
    int cl = u/NN, i = u - cl*NN, c = p + PBLK*cl;
    if (c < 256) accL[u] += inL[cl*NN+i]*dinv[i]*dinv[i] + bias[c];
  }
  __syncthreads();
  if (tid < NCOLS){
    int c = p + PBLK*tid;
    if (c < 256){
      const float* a = &accL[tid*NN];
      float m = 0.f;
      for (int i = 0; i < NN; i++) m += a[i];
      m *= (1.0f/NN);
      float v = 0.f;
      for (int i = 0; i < NN; i++){ float d = a[i]-m; v += d*d; }
      v *= (1.0f/NN);
      colstat[2*tid]   = m;
      colstat[2*tid+1] = 1.0f/sqrtf(v + 1e-5f);
    }
  }
  __syncthreads();
  for (int u = tid; u < NCOLS*NN; u += TPB){
    int cl = u/NN, i = u - cl*NN, c = p + PBLK*cl;
    if (c < 256){
      float hv = gamma[c]*(accL[u]-colstat[2*cl])*colstat[2*cl+1] + beta[c];
      outT[c*NN+i] = fmaxf(hv, 0.f);
    }
  }
}

__global__ __launch_bounds__(TPB, 1) void gvae_fused(
    const float* __restrict__ x,  const int* __restrict__ ei, const int* __restrict__ adj,
    const float* __restrict__ eps,
    const float* __restrict__ W1, const float* __restrict__ b1, const float* __restrict__ g1, const float* __restrict__ bt1,
    const float* __restrict__ W2, const float* __restrict__ b2, const float* __restrict__ g2, const float* __restrict__ bt2,
    const float* __restrict__ Wmu,const float* __restrict__ bmu,const float* __restrict__ Wlv,const float* __restrict__ blv,
    const float* __restrict__ We1,const float* __restrict__ be1,const float* __restrict__ We2,const float* __restrict__ be2,
    float* __restrict__ out, float* __restrict__ ws)
{
  const int tid = threadIdx.x;
  const int p   = blockIdx.x;

  // workspace layout (floats)
  int*   ctr   = (int*)ws;        // [0]        encoder barrier counter (memset 0)
  float* hT    = ws + 2048;       // [256*80]   layer-1 output, transposed
  float* h2T   = hT  + 20480;     // [256*80]   layer-2 output, transposed
  float* Bm    = h2T + 20480;     // [80*80]    B = sigmoid(A_hat), diag=1

  __shared__ float Xs[NN*RP];          // MPM: X, row-major [i][a]
  __shared__ float Ms[(NN+1)*RP];      // MPM: M, row-major + zero row at i=80
  __shared__ int   nbr[NN*NN];         // per-row byte-offset lists, interleaved [4q+r]
  __shared__ int   nmaxs[NN];          // padded list length per row
  __shared__ float degAs[NN];
  __shared__ float red[12];
  __shared__ float dinv[NN];
  __shared__ float accL[NCOLS*NN];
  __shared__ float hL[NCOLS*NN];
  __shared__ float gv[256], zv[128], t1v[256];
  __shared__ float colstat[2*NCOLS];

  // ---------------- E0: degrees (redundant per block) + GEMM1 x@W1 ----------
  for (int i = tid; i < NN; i += TPB) accL[i] = 1.0f;           // self loop
  __syncthreads();
  for (int e = tid; e < 800; e += TPB) atomicAdd(&accL[ei[800+e]], 1.0f);
  __syncthreads();
  for (int i = tid; i < NN; i += TPB) dinv[i] = 1.0f/sqrtf(accL[i]);
  __syncthreads();

  for (int u = tid; u < NCOLS*NN; u += TPB){
    int cl = u/NN, i = u - cl*NN, c = p + PBLK*cl;
    if (c < 256){
      float s = 0.f;
      for (int k = 0; k < 64; k++) s += x[i*64+k]*W1[k*256+c];
      hL[u] = s;
    }
  }
  __syncthreads();
  gcn_bn_relu(hL, hT, b1, g1, bt1, ei, dinv, accL, colstat, p, tid);
  gbar(ctr, 1*PBLK);                                   // hT complete (all cols)

  // ---------------- E2: GEMM2 h@W2 (reads all cols of hT) -------------------
  for (int u = tid; u < 20*NCOLS; u += TPB){
    int cl = u/20, iq = u - cl*20, c = p + PBLK*cl;
    if (c < 256){
      int i0 = 4*iq;
      float a0=0.f,a1=0.f,a2=0.f,a3=0.f;
      for (int k = 0; k < 256; k++){
        float wv = W2[k*256+c];
        float4 hv = *(const float4*)&hT[k*NN+i0];
        a0 += hv.x*wv; a1 += hv.y*wv; a2 += hv.z*wv; a3 += hv.w*wv;
      }
      hL[cl*NN+i0+0]=a0; hL[cl*NN+i0+1]=a1; hL[cl*NN+i0+2]=a2; hL[cl*NN+i0+3]=a3;
    }
  }
  __syncthreads();
  gcn_bn_relu(hL, h2T, b2, g2, bt2, ei, dinv, accL, colstat, p, tid);
  gbar(ctr, 2*PBLK);                                   // h2T complete

  // ---------------- E4: pool -> z -> t1 -> pair logits -> B -----------------
  for (int c = tid; c < 256; c += TPB){
    const float* r = &h2T[c*NN];
    float s = 0.f;
    for (int i = 0; i < NN; i++) s += r[i];
    gv[c] = s*(1.0f/NN);
  }
  __syncthreads();
  for (int c = tid; c < 128; c += TPB){
    float smu = bmu[c], slv = blv[c];
    for (int k = 0; k < 256; k++){
      float g = gv[k];
      smu += g*Wmu[k*128+c];
      slv += g*Wlv[k*128+c];
    }
    slv = fminf(fmaxf(slv, -4.f), 4.f);
    zv[c] = smu + eps[c]*expf(0.5f*slv);
  }
  __syncthreads();
  for (int c = tid; c < 256; c += TPB){
    float s = be1[c];
    for (int k = 0; k < 128; k++) s += zv[k]*We1[k*256+c];
    t1v[c] = fmaxf(s, 0.f);
  }
  __syncthreads();
  for (int r = 0; r < 4; r++){
    int i = p + PBLK*r;                                // rows p, p+20, p+40, p+60
    if (tid == 0) Bm[i*NN+i] = 1.0f;                   // diag forced to 1
    for (int j = i+1+tid; j < NN; j += TPB){
      int off = i*(2*NN-1-i)/2 + (j-i-1);              // triu(k=1) flat index
      float s = be2[off];
      for (int k = 0; k < 256; k++) s += t1v[k]*We2[k*3160+off];
      float sg = 1.0f/(1.0f + expf(-s));
      Bm[i*NN+j] = sg;
      Bm[j*NN+i] = sg;
    }
  }

  // ---- adjacency residue lists + degA (block 0; threads idle in E4's tail) --
  // A[i][j] = (adj|adj^T)!=0 or i==j. Lists store BYTE offsets of M rows,
  // interleaved by residue r=j&3 (ascending j within each residue == exactly
  // the e0..e3 accumulation order of the r0-r6 kernels). Rows padded to a
  // common length L with offsets of the zero row (adds exact +0.0).
  if (p == 0 && tid >= 128 && tid < 128+NN){
    int i = tid - 128;
    float dg = 0.f;
    int cnt[4];
    #pragma unroll
    for (int r = 0; r < 4; r++){
      int c = 0;
      for (int q = 0; q < 20; q++){
        int j = 4*q + r;
        bool e = ((adj[i*NN+j] | adj[j*NN+i]) != 0) || (i == j);
        if (e){ nbr[i*NN + 4*c + r] = j*RP*4; c++; dg += 1.f; }
      }
      cnt[r] = c;
    }
    int L01 = cnt[0] > cnt[1] ? cnt[0] : cnt[1];
    int L23 = cnt[2] > cnt[3] ? cnt[2] : cnt[3];
    int L   = L01 > L23 ? L01 : L23;
    #pragma unroll
    for (int r = 0; r < 4; r++)
      for (int q = cnt[r]; q < L; q++) nbr[i*NN + 4*q + r] = NN*RP*4;  // zero row
    nmaxs[i] = L;
    degAs[i] = dg;
  }

  // ---- release encoder outputs; blocks 1..19 exit; block 0 acquires --------
  __syncthreads();
  if (tid == 0) __hip_atomic_fetch_add(ctr, 1, __ATOMIC_RELEASE, AGT);
  if (p != 0) return;
  if (tid == 0){
    int spins = 0;
    while (__hip_atomic_load(ctr, __ATOMIC_RELAXED, AGT) < 3*PBLK){
      __builtin_amdgcn_s_sleep(1);
      if (++spins > SPIN_MAX) break;
    }
    (void)__hip_atomic_load(ctr, __ATOMIC_ACQUIRE, AGT);
  }
  __syncthreads();                     // Bm visible; nbr/degAs/nmaxs built

  // ---------------- MPM on ONE CU: thread <-> (a, rows i0+8k) ---------------
  const int w  = tid >> 6;
  const int l  = tid & 63;
  const int a  = tid % NN;             // 640 = 8*80: exact cover
  const int i0 = tid / NN;             // 0..7

  // B row a -> 80 VGPRs (+ degB incl diag, then zero diag element: b==a excl.)
  float4 Bf[20]; float degB = 0.f;
  #pragma unroll
  for (int c = 0; c < 20; c++){
    float4 b = *(const float4*)&Bm[a*NN+4*c];
    Bf[c] = b;
    degB += (b.x+b.y)+(b.z+b.w);
  }
  #pragma unroll
  for (int c = 0; c < 20; c++){
    if (c == (a>>2)){
      int e = a & 3;
      if      (e == 0) Bf[c].x = 0.f;
      else if (e == 1) Bf[c].y = 0.f;
      else if (e == 2) Bf[c].z = 0.f;
      else             Bf[c].w = 0.f;
    }
  }

  for (int u = tid; u < NN*RP; u += TPB) Xs[u] = 1.0f/NN;     // X0 = 1/n
  for (int u = tid; u < RP; u += TPB)   Ms[NN*RP + u] = 0.f;  // zero row
  __syncthreads();

  const char* MsB = (const char*)Ms + 4*a;   // column-a base for offset lists
  float sc = 1.0f;                     // 1/||R_{t-1}|| applied one step late
  for (int t = 0; t < 50; t++){
    // phase 1: M[i][a] = max_{b != a} X[i][b]*B[a][b]  (own 10 rows)
    for (int k = 0; k < 10; k++){
      int i = i0 + 8*k;
      const float4* xr = (const float4*)&Xs[i*RP];
      float m = 0.f;
      #pragma unroll
      for (int c = 0; c < 20; c++){
        float4 pr = xr[c] * Bf[c];                       // 2x v_pk_mul_f32
        m = fmaxf(fmaxf(pr.x, pr.y), fmaxf(fmaxf(pr.z, pr.w), m));  // max3 x2
      }
      Ms[i*RP + a] = m;
    }
    __syncthreads();                   // b1: Ms complete

    // phase 2: edge + xn (exact e0..e3 residue order; pads add +0.0)
    float part = 0.f;
    for (int k = 0; k < 10; k++){
      int i = i0 + 8*k;
      const int4* lst = (const int4*)&nbr[i*NN];
      int L = nmaxs[i];
      float e0=0.f, e1=0.f, e2=0.f, e3=0.f;
      for (int q = 0; q < L; q++){
        int4 o = lst[q];
        e0 += *(const float*)(MsB + o.x);
        e1 += *(const float*)(MsB + o.y);
        e2 += *(const float*)(MsB + o.z);
        e3 += *(const float*)(MsB + o.w);
      }
      float msl   = Ms[i*RP + a];
      float edge  = ((e0+e1)+(e2+e3)) - msl;
      float nsv   = 1.0f/(fabsf(degAs[i]-degB)+1.0f);
      float xnode = Xs[i*RP + a];
      float xn    = sc*(nsv*xnode + edge);   // R_{t+1} = f(R_t/||R_t||)
      Xs[i*RP + a] = xn;                     // own entry; next read after b2
      part += xn*xn;
    }
    float v = wave_sum(part);
    if (l == 0) red[w] = v;
    __syncthreads();                   // b2: red + Xs(t+1) complete
    float tot = (((red[0]+red[1])+(red[2]+red[3])) +
                 ((red[4]+red[5])+(red[6]+red[7]))) + (red[8]+red[9]);
    sc = 1.0f/sqrtf(tot);
  }

  // final normalization + output (block 0 covers all 6400 entries)
  for (int k = 0; k < 10; k++){
    int i = i0 + 8*k;
    out[i*NN + a] = Xs[i*RP + a]*sc;
  }
}

extern "C" void kernel_launch(void* const* d_in, const int* in_sizes, int n_in,
                              void* d_out, int out_size, void* d_ws, size_t ws_size,
                              hipStream_t stream)
{
  (void)in_sizes; (void)n_in; (void)out_size; (void)ws_size;
  (void)hipMemsetAsync(d_ws, 0, 512, stream);   // barrier counter region
  gvae_fused<<<PBLK, TPB, 0, stream>>>(
      (const float*)d_in[0],  (const int*)d_in[1],   (const int*)d_in[2],   (const float*)d_in[3],
      (const float*)d_in[4],  (const float*)d_in[5],  (const float*)d_in[6],  (const float*)d_in[7],
      (const float*)d_in[8],  (const float*)d_in[9],  (const float*)d_in[10], (const float*)d_in[11],
      (const float*)d_in[12], (const float*)d_in[13], (const float*)d_in[14], (const float*)d_in[15],
      (const float*)d_in[16], (const float*)d_in[17], (const float*)d_in[18], (const float*)d_in[19],
      (float*)d_out, (float*)d_ws);
}

// Round 8
// 491.723 us; speedup vs baseline: 2.9740x; 2.9740x over previous
//
#include <hip/hip_runtime.h>

// GraphVAE: GCN-VAE encoder + edge decoder + 50-iter MPM fixed point, fused
// into ONE persistent 20-block kernel.
//
// Round-8 = recombination of the two measured-best protocol halves:
//  * r2's sync core (BEST at 402us): wave0-ONLY latched flag poll (20
//    streams; r4's 100 and r6's 640 streams both regressed), s_sleep
//    backoff, ONE acquire (buffer_inv) after detect, CACHED reload.
//  * r4's conflict-free data path: ROW-major exchange buffer -> reload is
//    a linear copy (cached f4 loads, near-linear LDS writes). Kills r2's
//    1.76M reload-transpose bank conflicts (~0.7us/iter).
//  * store side (r4-proven): wave0 stores the block's 4 columns as 80
//    uncached 16B granules + vmcnt(0) drain, then lane0 publishes the norm
//    partial as the arrival flag. Flag value doubles as the norm partial
//    (deterministic fixed-order reduction; absmax 0.0 chain preserved).
//  * SPIN_MAX on all global spins (r5 lesson: finite-wrong beats hang).

#define NN 80
#define PBLK 20            // blocks (each owns 4 columns of X) - all co-resident
#define TPB 320            // 5 full waves; lane <-> one (i,a) output
#define RP 84              // LDS row pad: conflict-free b128 row reads
#define NCOLS 13           // max owned feature columns per block (256/20 rounded up)
#define AGT __HIP_MEMORY_SCOPE_AGENT
#define SPIN_MAX (1<<22)   // hang-breaker

typedef float f4 __attribute__((ext_vector_type(4)));   // register-legal for asm

__device__ __forceinline__ void gbar(int* ctr, int target){
  __syncthreads();
  if (threadIdx.x == 0){
    __hip_atomic_fetch_add(ctr, 1, __ATOMIC_RELEASE, AGT);
    int spins = 0;
    while (__hip_atomic_load(ctr, __ATOMIC_RELAXED, AGT) < target){
      __builtin_amdgcn_s_sleep(1);
      if (++spins > SPIN_MAX) break;
    }
    (void)__hip_atomic_load(ctr, __ATOMIC_ACQUIRE, AGT);  // one inv, not per-poll
  }
  __syncthreads();
}

__device__ __forceinline__ float wave_sum(float v){
  #pragma unroll
  for (int k = 32; k >= 1; k >>= 1) v += __shfl_xor(v, k, 64);
  return v;
}

__device__ __forceinline__ void stg_uc(f4* p, f4 v){
  asm volatile("global_store_dwordx4 %0, %1, off sc0 sc1 nt"
               :: "v"(p), "v"(v) : "memory");
}

// GCN aggregate (+self loop) + bias + BatchNorm(train, biased var) + ReLU for
// this block's owned feature columns. inL: LDS [NCOLS][80] (pre-aggregation,
// own columns). outT: global transposed [256][80].
__device__ void gcn_bn_relu(const float* inL, float* outT,
                            const float* bias, const float* gamma, const float* beta,
                            const int* ei, const float* dinv,
                            float* accL, float* colstat, int p, int tid)
{
  for (int u = tid; u < NCOLS*NN; u += TPB) accL[u] = 0.f;
  __syncthreads();
  for (int cl = 0; cl < NCOLS; cl++){
    int c = p + PBLK*cl; if (c >= 256) break;
    const float* col = &inL[cl*NN];
    for (int e = tid; e < 800; e += TPB){
      int sidx = ei[e], didx = ei[800+e];
      atomicAdd(&accL[cl*NN + didx], col[sidx]*dinv[sidx]*dinv[didx]);
    }
  }
  __syncthreads();
  for (int u = tid; u < NCOLS*NN; u += TPB){
    int cl = u/NN, i = u - cl*NN, c = p + PBLK*cl;
    if (c < 256) accL[u] += inL[cl*NN+i]*dinv[i]*dinv[i] + bias[c];
  }
  __syncthreads();
  if (tid < NCOLS){
    int c = p + PBLK*tid;
    if (c < 256){
      const float* a = &accL[tid*NN];
      float m = 0.f;
      for (int i = 0; i < NN; i++) m += a[i];
      m *= (1.0f/NN);
      float v = 0.f;
      for (int i = 0; i < NN; i++){ float d = a[i]-m; v += d*d; }
      v *= (1.0f/NN);
      colstat[2*tid]   = m;
      colstat[2*tid+1] = 1.0f/sqrtf(v + 1e-5f);
    }
  }
  __syncthreads();
  for (int u = tid; u < NCOLS*NN; u += TPB){
    int cl = u/NN, i = u - cl*NN, c = p + PBLK*cl;
    if (c < 256){
      float hv = gamma[c]*(accL[u]-colstat[2*cl])*colstat[2*cl+1] + beta[c];
      outT[c*NN+i] = fmaxf(hv, 0.f);
    }
  }
}

__global__ __launch_bounds__(TPB, 1) void gvae_fused(
    const float* __restrict__ x,  const int* __restrict__ ei, const int* __restrict__ adj,
    const float* __restrict__ eps,
    const float* __restrict__ W1, const float* __restrict__ b1, const float* __restrict__ g1, const float* __restrict__ bt1,
    const float* __restrict__ W2, const float* __restrict__ b2, const float* __restrict__ g2, const float* __restrict__ bt2,
    const float* __restrict__ Wmu,const float* __restrict__ bmu,const float* __restrict__ Wlv,const float* __restrict__ blv,
    const float* __restrict__ We1,const float* __restrict__ be1,const float* __restrict__ We2,const float* __restrict__ be2,
    float* __restrict__ out, float* __restrict__ ws)
{
  const int tid = threadIdx.x;
  const int p   = blockIdx.x;

  // workspace layout (floats)
  int*   ctr   = (int*)ws;        // [0]        encoder barrier counter (memset 0)
  float* flags = ws + 64;         // [50*32]    per-iter per-block flag/partial (memset 0)
  float* Xb0   = ws + 2048;       // [80*80]    MPM ping (ROW-major: X[i*80+a])
  float* Xb1   = Xb0 + 6400;      // [80*80]    MPM pong
  float* hT    = Xb1 + 6400;      // [256*80]   layer-1 output, transposed
  float* h2T   = hT  + 20480;     // [256*80]   layer-2 output, transposed
  float* Bm    = h2T + 20480;     // [80*80]    B = sigmoid(A_hat), diag=1

  __shared__ float Xs[NN*RP];        // MPM: X tile, row-major [i][a], pad 84
  __shared__ float MtL[4*RP];        // MPM: M^T (own 4 columns)
  __shared__ float red[8];
  __shared__ float dinv[NN];
  __shared__ __align__(16) float accL[NCOLS*NN];   // reused as MPM store staging [i][4]
  __shared__ float hL[NCOLS*NN];     // own-column staging between GEMM and GCN
  __shared__ float gv[256], zv[128], t1v[256];
  __shared__ float colstat[2*NCOLS];

  // ---------------- E0: degrees (redundant per block) + GEMM1 x@W1 ----------
  for (int i = tid; i < NN; i += TPB) accL[i] = 1.0f;           // self loop
  __syncthreads();
  for (int e = tid; e < 800; e += TPB) atomicAdd(&accL[ei[800+e]], 1.0f);
  __syncthreads();
  for (int i = tid; i < NN; i += TPB) dinv[i] = 1.0f/sqrtf(accL[i]);
  __syncthreads();

  for (int u = tid; u < NCOLS*NN; u += TPB){
    int cl = u/NN, i = u - cl*NN, c = p + PBLK*cl;
    if (c < 256){
      float s = 0.f;
      for (int k = 0; k < 64; k++) s += x[i*64+k]*W1[k*256+c];
      hL[u] = s;
    }
  }
  __syncthreads();
  gcn_bn_relu(hL, hT, b1, g1, bt1, ei, dinv, accL, colstat, p, tid);
  gbar(ctr, 1*PBLK);                                   // hT complete (all cols)

  // ---------------- E2: GEMM2 h@W2 (reads all cols of hT) -------------------
  for (int u = tid; u < 20*NCOLS; u += TPB){
    int cl = u/20, iq = u - cl*20, c = p + PBLK*cl;
    if (c < 256){
      int i0 = 4*iq;
      float a0=0.f,a1=0.f,a2=0.f,a3=0.f;
      for (int k = 0; k < 256; k++){
        float wv = W2[k*256+c];
        float4 hv = *(const float4*)&hT[k*NN+i0];
        a0 += hv.x*wv; a1 += hv.y*wv; a2 += hv.z*wv; a3 += hv.w*wv;
      }
      hL[cl*NN+i0+0]=a0; hL[cl*NN+i0+1]=a1; hL[cl*NN+i0+2]=a2; hL[cl*NN+i0+3]=a3;
    }
  }
  __syncthreads();
  gcn_bn_relu(hL, h2T, b2, g2, bt2, ei, dinv, accL, colstat, p, tid);
  gbar(ctr, 2*PBLK);                                   // h2T complete

  // ---------------- E4: pool -> z -> t1 -> pair logits -> B -----------------
  for (int c = tid; c < 256; c += TPB){
    const float* r = &h2T[c*NN];
    float s = 0.f;
    for (int i = 0; i < NN; i++) s += r[i];
    gv[c] = s*(1.0f/NN);
  }
  __syncthreads();
  for (int c = tid; c < 128; c += TPB){
    float smu = bmu[c], slv = blv[c];
    for (int k = 0; k < 256; k++){
      float g = gv[k];
      smu += g*Wmu[k*128+c];
      slv += g*Wlv[k*128+c];
    }
    slv = fminf(fmaxf(slv, -4.f), 4.f);
    zv[c] = smu + eps[c]*expf(0.5f*slv);
  }
  __syncthreads();
  for (int c = tid; c < 256; c += TPB){
    float s = be1[c];
    for (int k = 0; k < 128; k++) s += zv[k]*We1[k*256+c];
    t1v[c] = fmaxf(s, 0.f);
  }
  __syncthreads();
  for (int r = 0; r < 4; r++){
    int i = p + PBLK*r;                                // rows p, p+20, p+40, p+60
    if (tid == 0) Bm[i*NN+i] = 1.0f;                   // diag forced to 1
    for (int j = i+1+tid; j < NN; j += TPB){
      int off = i*(2*NN-1-i)/2 + (j-i-1);              // triu(k=1) flat index
      float s = be2[off];
      for (int k = 0; k < 256; k++) s += t1v[k]*We2[k*3160+off];
      float sg = 1.0f/(1.0f + expf(-s));
      Bm[i*NN+j] = sg;
      Bm[j*NN+i] = sg;
    }
  }
  gbar(ctr, 3*PBLK);                                   // Bm complete

  // ---------------- E5: per-lane register caches for the MPM loop -----------
  const int w  = tid >> 6;
  const int l  = tid & 63;
  const int il = 16*w + (l & 15);    // this lane's row i (== j in M phase)
  const int ae = l >> 4;             // local column index 0..3
  const int al = 4*p + ae;           // this lane's column a

  float4 Af[20], Bf[20];
  float degA = 0.f, degB = 0.f;
  #pragma unroll
  for (int c = 0; c < 20; c++){
    int j0 = 4*c;
    int4 ar = *(const int4*)&adj[il*NN+j0];
    int q0 = adj[(j0+0)*NN+il];
    int q1 = adj[(j0+1)*NN+il];
    int q2 = adj[(j0+2)*NN+il];
    int q3 = adj[(j0+3)*NN+il];
    float4 a;
    a.x = ((ar.x|q0) != 0 || il == j0+0) ? 1.f : 0.f;
    a.y = ((ar.y|q1) != 0 || il == j0+1) ? 1.f : 0.f;
    a.z = ((ar.z|q2) != 0 || il == j0+2) ? 1.f : 0.f;
    a.w = ((ar.w|q3) != 0 || il == j0+3) ? 1.f : 0.f;
    Af[c] = a;
    degA += (a.x+a.y)+(a.z+a.w);
  }
  #pragma unroll
  for (int c = 0; c < 20; c++){
    float4 b = *(const float4*)&Bm[al*NN+4*c];
    Bf[c] = b;
    degB += (b.x+b.y)+(b.z+b.w);
  }
  const float ns = 1.0f/(fabsf(degA-degB)+1.0f);
  // b==a exclusion: zero B[a][a] in the register cache (valid since X,B >= 0)
  #pragma unroll
  for (int c = 0; c < 20; c++){
    if (c == p){
      if      (ae == 0) Bf[c].x = 0.f;
      else if (ae == 1) Bf[c].y = 0.f;
      else if (ae == 2) Bf[c].z = 0.f;
      else              Bf[c].w = 0.f;
    }
  }

  // ---------------- MPM: 50 iterations ---------------------------------------
  for (int u = tid; u < NN*RP; u += TPB) Xs[u] = 1.0f/NN;   // X0 = 1/n
  __syncthreads();
  float xn = 0.f;
  float sc = 1.0f;                    // 1/||R_{t-1}|| applied one step late
  for (int t = 0; t < 50; t++){
    // M[il][al] = max_{b != al} X[il][b]*B[al][b]
    float m = 0.f;
    #pragma unroll
    for (int c = 0; c < 20; c++){
      float4 xv = *(const float4*)&Xs[il*RP+4*c];
      float p0 = xv.x*Bf[c].x, p1 = xv.y*Bf[c].y, p2 = xv.z*Bf[c].z, p3 = xv.w*Bf[c].w;
      m = fmaxf(m, fmaxf(fmaxf(p0,p1), fmaxf(p2,p3)));
    }
    float xnode = Xs[il*RP+al];
    MtL[ae*RP+il] = m;
    __syncthreads();                  // b1: MtL ready (Xs dead after this)

    // edge[il][al] = sum_j A[il][j]*M[j][al] - M[il][al]   (A[i][i] = 1)
    float e0=0.f,e1=0.f,e2=0.f,e3=0.f;
    #pragma unroll
    for (int c = 0; c < 20; c++){
      float4 mv = *(const float4*)&MtL[ae*RP+4*c];
      e0 += Af[c].x*mv.x; e1 += Af[c].y*mv.y; e2 += Af[c].z*mv.z; e3 += Af[c].w*mv.w;
    }
    float edge = ((e0+e1)+(e2+e3)) - m;
    xn = sc*(ns*xnode + edge);        // R_{t+1} = f(R_t / ||R_t||)

    // stage xn ROW-major in LDS: accL[i*4 + ae] (<=2-way banks = free)
    if (t < 49) accL[4*il + ae] = xn;
    float v = wave_sum(xn*xn);
    if (l == 0) red[w] = v;
    __syncthreads();                  // b2: staging + red[] ready

    // wave0: uncached X store (80 x 16B granules) + drain + flag + poll + inv
    if (w == 0){
      if (t < 49){
        float* Xdst = (t&1) ? Xb1 : Xb0;
        f4 s0 = *(const f4*)&accL[4*l];
        stg_uc((f4*)&Xdst[l*NN+4*p], s0);
        if (l < 16){
          f4 s1 = *(const f4*)&accL[4*(64+l)];
          stg_uc((f4*)&Xdst[(64+l)*NN+4*p], s1);
        }
        asm volatile("s_waitcnt vmcnt(0)" ::: "memory");
      }
      if (l == 0){
        float part = ((red[0]+red[1])+(red[2]+red[3]))+red[4];   // > 0 always
        __hip_atomic_store(&flags[t*32+p], part, __ATOMIC_RELAXED, AGT);
      }
      // latched 20-stream poll with backoff (r2's winning shape)
      float fv = 0.f;
      int spins = 0;
      for (;;){
        if (l < PBLK && fv == 0.f)
          fv = __hip_atomic_load(&flags[t*32+l], __ATOMIC_RELAXED, AGT);
        if (__all((l >= PBLK) || (fv != 0.f))) break;
        if (++spins > SPIN_MAX) break;
        __builtin_amdgcn_s_sleep(1);
      }
      float tot = wave_sum((l < PBLK) ? fv : 0.f);   // ||R_{t+1}||^2, fixed order
      if (l == 0){
        red[5] = tot;
        // one acquire -> buffer_inv (L1+L2); cached reload below then
        // refetches the uncached X stores from the coherence point.
        (void)__hip_atomic_load(&flags[t*32], __ATOMIC_ACQUIRE, AGT);
      }
    }
    __syncthreads();                  // b3: inv done; red[5] ready
    sc = 1.0f/sqrtf(red[5]);

    if (t < 49){
      // cached LINEAR reload (row-major buffer): 5 coalesced f4 loads per
      // thread, near-linear LDS writes -> no transpose scatter conflicts.
      const f4* S4 = (const f4*)((t&1) ? Xb1 : Xb0);
      #pragma unroll
      for (int c5 = 0; c5 < 5; c5++){
        int q = tid + TPB*c5;
        f4 v4 = S4[q];
        int i = q/20, a0 = 4*(q - 20*i);
        *(f4*)&Xs[i*RP + a0] = v4;
      }
    }
    __syncthreads();                  // b4: Xs(t+1) staged
  }
  out[il*NN+al] = xn*sc;              // final normalization
}

extern "C" void kernel_launch(void* const* d_in, const int* in_sizes, int n_in,
                              void* d_out, int out_size, void* d_ws, size_t ws_size,
                              hipStream_t stream)
{
  (void)in_sizes; (void)n_in; (void)out_size; (void)ws_size;
  // zero barrier counter + 50*32 flag slots (ws re-poisoned each launch)
  (void)hipMemsetAsync(d_ws, 0, 8192, stream);
  gvae_fused<<<PBLK, TPB, 0, stream>>>(
      (const float*)d_in[0],  (const int*)d_in[1],   (const int*)d_in[2],   (const float*)d_in[3],
      (const float*)d_in[4],  (const float*)d_in[5],  (const float*)d_in[6],  (const float*)d_in[7],
      (const float*)d_in[8],  (const float*)d_in[9],  (const float*)d_in[10], (const float*)d_in[11],
      (const float*)d_in[12], (const float*)d_in[13], (const float*)d_in[14], (const float*)d_in[15],
      (const float*)d_in[16], (const float*)d_in[17], (const float*)d_in[18], (const float*)d_in[19],
      (float*)d_out, (float*)d_ws);
}